// Round 2
// baseline (1204.001 us; speedup 1.0000x reference)
//
#include <hip/hip_runtime.h>

#define NS 4096
#define NT 8192
#define DIN 256
#define DOUT 128
#define CHUNK 2048

// float offsets into workspace
#define OFF_RS   0
#define OFF_RT   (NS)                    // 4096: holds deg_to, then rt in place
#define OFF_C1   (OFF_RT + NT)           // 12288
#define OFF_C2   (OFF_C1 + NS*DOUT)      // 536576
#define OFF_XS   (OFF_C2 + NT*DOUT)      // 1585152
#define OFF_YS   (OFF_XS + NS*DOUT)
#define OFF_XNS  (OFF_YS + NT*DOUT)

__global__ void zero_kernel(float* __restrict__ p, int n4) {
    int i = blockIdx.x * blockDim.x + threadIdx.x;
    int stride = gridDim.x * blockDim.x;
    float4* p4 = (float4*)p;
    float4 z = make_float4(0.f, 0.f, 0.f, 0.f);
    for (; i < n4; i += stride) p4[i] = z;
}

// rs[i] = sqrt(1 + sum_t adj[i,t] + sum_j adj_s[i,j]); one block per row
__global__ void rowsum_rs_kernel(const float* __restrict__ adj,
                                 const float* __restrict__ adj_s,
                                 float* __restrict__ rs) {
    int row = blockIdx.x;
    int tid = threadIdx.x;  // 256
    const float4* a = (const float4*)(adj + (size_t)row * NT);
    const float4* b = (const float4*)(adj_s + (size_t)row * NS);
    float sum = 0.f;
    for (int c = tid; c < NT / 4; c += 256) { float4 v = a[c]; sum += v.x + v.y + v.z + v.w; }
    for (int c = tid; c < NS / 4; c += 256) { float4 v = b[c]; sum += v.x + v.y + v.z + v.w; }
    __shared__ float red[4];
    for (int off = 32; off > 0; off >>= 1) sum += __shfl_down(sum, off, 64);
    if ((tid & 63) == 0) red[tid >> 6] = sum;
    __syncthreads();
    if (tid == 0) {
        rs[row] = sqrtf(red[0] + red[1] + red[2] + red[3] + 1.0f);
    }
}

// partial column sums, atomically accumulated into deg[t]
__global__ void colsum_kernel(const float* __restrict__ A, int nrows, int ncols,
                              int rows_per_chunk, float* __restrict__ deg) {
    int t = blockIdx.x * blockDim.x + threadIdx.x;
    int r0 = blockIdx.y * rows_per_chunk;
    int r1 = r0 + rows_per_chunk;
    if (r1 > nrows) r1 = nrows;
    float sum = 0.f;
    for (int r = r0; r < r1; ++r) sum += A[(size_t)r * ncols + t];
    unsafeAtomicAdd(&deg[t], sum);
}

__global__ void finish_rt_kernel(float* __restrict__ rt) {
    int t = blockIdx.x * blockDim.x + threadIdx.x;
    if (t < NT) rt[t] = sqrtf(rt[t] + 1.0f);
}

// out[m, :] = (inp[m, :] @ W) / rdeg[m];  inp [M, 256], W [256, 128]
__global__ __launch_bounds__(256)
void proj_scale_kernel(const float* __restrict__ inp,
                       const float* __restrict__ W,
                       const float* __restrict__ rdeg,
                       float* __restrict__ outp) {
    __shared__ float As[32][68];
    __shared__ float Bs[32][128];
    const int tid = threadIdx.x;
    const int m0 = blockIdx.x * 64;
    const int tx = tid & 15, ty = tid >> 4;
    const int arow = tid >> 3, acg = tid & 7;
    const int bk = tid >> 5, bng = tid & 31;

    float acc[4][8];
#pragma unroll
    for (int r = 0; r < 4; ++r)
#pragma unroll
        for (int c = 0; c < 8; ++c) acc[r][c] = 0.f;

    for (int kt = 0; kt < DIN; kt += 32) {
        const float* Ab = inp + (size_t)(m0 + arow) * DIN + kt + acg * 4;
        float4 a0 = *(const float4*)Ab;
        float4 a1 = *(const float4*)(Ab + (size_t)32 * DIN);
        const float* Bb = W + (size_t)(kt + bk) * DOUT + bng * 4;
        float4 b0 = *(const float4*)Bb;
        float4 b1 = *(const float4*)(Bb + 8 * DOUT);
        float4 b2 = *(const float4*)(Bb + 16 * DOUT);
        float4 b3 = *(const float4*)(Bb + 24 * DOUT);
        __syncthreads();
        As[acg * 4 + 0][arow] = a0.x;
        As[acg * 4 + 1][arow] = a0.y;
        As[acg * 4 + 2][arow] = a0.z;
        As[acg * 4 + 3][arow] = a0.w;
        As[acg * 4 + 0][arow + 32] = a1.x;
        As[acg * 4 + 1][arow + 32] = a1.y;
        As[acg * 4 + 2][arow + 32] = a1.z;
        As[acg * 4 + 3][arow + 32] = a1.w;
        *(float4*)&Bs[bk][bng * 4] = b0;
        *(float4*)&Bs[bk + 8][bng * 4] = b1;
        *(float4*)&Bs[bk + 16][bng * 4] = b2;
        *(float4*)&Bs[bk + 24][bng * 4] = b3;
        __syncthreads();
#pragma unroll
        for (int k = 0; k < 32; ++k) {
            float4 av = *(const float4*)&As[k][ty * 4];
            float4 bv0 = *(const float4*)&Bs[k][tx * 4];
            float4 bv1 = *(const float4*)&Bs[k][tx * 4 + 64];
            float a[4] = {av.x, av.y, av.z, av.w};
            float b[8] = {bv0.x, bv0.y, bv0.z, bv0.w, bv1.x, bv1.y, bv1.z, bv1.w};
#pragma unroll
            for (int r = 0; r < 4; ++r)
#pragma unroll
                for (int c = 0; c < 8; ++c) acc[r][c] = fmaf(a[r], b[c], acc[r][c]);
        }
    }
#pragma unroll
    for (int r = 0; r < 4; ++r) {
        int row = m0 + ty * 4 + r;
        float rd = rdeg[row];
        float* orow = outp + (size_t)row * DOUT;
#pragma unroll
        for (int c = 0; c < 4; ++c) {
            orow[tx * 4 + c] = acc[r][c] / rd;
            orow[tx * 4 + 64 + c] = acc[r][4 + c] / rd;
        }
    }
}

// C[m0:m0+64, 0:128] += A[m0:m0+64, k0:k0+CHUNK] @ B[k0:k0+CHUNK, 0:128]
__global__ __launch_bounds__(256)
void gemm_nn_kernel(const float* __restrict__ A, int lda,
                    const float* __restrict__ B,
                    float* __restrict__ C) {
    __shared__ float As[32][68];
    __shared__ float Bs[32][128];
    const int tid = threadIdx.x;
    const int m0 = blockIdx.x * 64;
    const int k0 = blockIdx.y * CHUNK;
    const int tx = tid & 15, ty = tid >> 4;
    const int arow = tid >> 3, acg = tid & 7;
    const int bk = tid >> 5, bng = tid & 31;

    float acc[4][8];
#pragma unroll
    for (int r = 0; r < 4; ++r)
#pragma unroll
        for (int c = 0; c < 8; ++c) acc[r][c] = 0.f;

    for (int kt = 0; kt < CHUNK; kt += 32) {
        const float* Ab = A + (size_t)(m0 + arow) * lda + (k0 + kt + acg * 4);
        float4 a0 = *(const float4*)Ab;
        float4 a1 = *(const float4*)(Ab + (size_t)32 * lda);
        const float* Bb = B + (size_t)(k0 + kt + bk) * DOUT + bng * 4;
        float4 b0 = *(const float4*)Bb;
        float4 b1 = *(const float4*)(Bb + 8 * DOUT);
        float4 b2 = *(const float4*)(Bb + 16 * DOUT);
        float4 b3 = *(const float4*)(Bb + 24 * DOUT);
        __syncthreads();
        As[acg * 4 + 0][arow] = a0.x;
        As[acg * 4 + 1][arow] = a0.y;
        As[acg * 4 + 2][arow] = a0.z;
        As[acg * 4 + 3][arow] = a0.w;
        As[acg * 4 + 0][arow + 32] = a1.x;
        As[acg * 4 + 1][arow + 32] = a1.y;
        As[acg * 4 + 2][arow + 32] = a1.z;
        As[acg * 4 + 3][arow + 32] = a1.w;
        *(float4*)&Bs[bk][bng * 4] = b0;
        *(float4*)&Bs[bk + 8][bng * 4] = b1;
        *(float4*)&Bs[bk + 16][bng * 4] = b2;
        *(float4*)&Bs[bk + 24][bng * 4] = b3;
        __syncthreads();
#pragma unroll
        for (int k = 0; k < 32; ++k) {
            float4 av = *(const float4*)&As[k][ty * 4];
            float4 bv0 = *(const float4*)&Bs[k][tx * 4];
            float4 bv1 = *(const float4*)&Bs[k][tx * 4 + 64];
            float a[4] = {av.x, av.y, av.z, av.w};
            float b[8] = {bv0.x, bv0.y, bv0.z, bv0.w, bv1.x, bv1.y, bv1.z, bv1.w};
#pragma unroll
            for (int r = 0; r < 4; ++r)
#pragma unroll
                for (int c = 0; c < 8; ++c) acc[r][c] = fmaf(a[r], b[c], acc[r][c]);
        }
    }
#pragma unroll
    for (int r = 0; r < 4; ++r) {
        float* Crow = C + (size_t)(m0 + ty * 4 + r) * DOUT;
#pragma unroll
        for (int c = 0; c < 4; ++c) {
            unsafeAtomicAdd(Crow + tx * 4 + c, acc[r][c]);
            unsafeAtomicAdd(Crow + tx * 4 + 64 + c, acc[r][4 + c]);
        }
    }
}

// C[m0:m0+64, :] += A[k0:k0+CHUNK, m0:m0+64]^T @ B[k0:k0+CHUNK, :]
// A = adj [NS, NT] row-major; output rows are columns of adj
__global__ __launch_bounds__(256)
void gemm_tn_kernel(const float* __restrict__ A,
                    const float* __restrict__ B,
                    float* __restrict__ C) {
    __shared__ float As[32][68];
    __shared__ float Bs[32][128];
    const int tid = threadIdx.x;
    const int m0 = blockIdx.x * 64;
    const int k0 = blockIdx.y * CHUNK;
    const int tx = tid & 15, ty = tid >> 4;
    const int akk = tid >> 4, amg = tid & 15;
    const int bk = tid >> 5, bng = tid & 31;

    float acc[4][8];
#pragma unroll
    for (int r = 0; r < 4; ++r)
#pragma unroll
        for (int c = 0; c < 8; ++c) acc[r][c] = 0.f;

    for (int kt = 0; kt < CHUNK; kt += 32) {
        const float* Ab = A + (size_t)(k0 + kt + akk) * NT + m0 + amg * 4;
        float4 a0 = *(const float4*)Ab;
        float4 a1 = *(const float4*)(Ab + (size_t)16 * NT);
        const float* Bb = B + (size_t)(k0 + kt + bk) * DOUT + bng * 4;
        float4 b0 = *(const float4*)Bb;
        float4 b1 = *(const float4*)(Bb + 8 * DOUT);
        float4 b2 = *(const float4*)(Bb + 16 * DOUT);
        float4 b3 = *(const float4*)(Bb + 24 * DOUT);
        __syncthreads();
        *(float4*)&As[akk][amg * 4] = a0;
        *(float4*)&As[akk + 16][amg * 4] = a1;
        *(float4*)&Bs[bk][bng * 4] = b0;
        *(float4*)&Bs[bk + 8][bng * 4] = b1;
        *(float4*)&Bs[bk + 16][bng * 4] = b2;
        *(float4*)&Bs[bk + 24][bng * 4] = b3;
        __syncthreads();
#pragma unroll
        for (int k = 0; k < 32; ++k) {
            float4 av = *(const float4*)&As[k][ty * 4];
            float4 bv0 = *(const float4*)&Bs[k][tx * 4];
            float4 bv1 = *(const float4*)&Bs[k][tx * 4 + 64];
            float a[4] = {av.x, av.y, av.z, av.w};
            float b[8] = {bv0.x, bv0.y, bv0.z, bv0.w, bv1.x, bv1.y, bv1.z, bv1.w};
#pragma unroll
            for (int r = 0; r < 4; ++r)
#pragma unroll
                for (int c = 0; c < 8; ++c) acc[r][c] = fmaf(a[r], b[c], acc[r][c]);
        }
    }
#pragma unroll
    for (int r = 0; r < 4; ++r) {
        float* Crow = C + (size_t)(m0 + ty * 4 + r) * DOUT;
#pragma unroll
        for (int c = 0; c < 4; ++c) {
            unsafeAtomicAdd(Crow + tx * 4 + c, acc[r][c]);
            unsafeAtomicAdd(Crow + tx * 4 + 64 + c, acc[r][4 + c]);
        }
    }
}

// x_new = relu(xs + C1/rs) -> d_out;  xns = x_new/rs -> ws
__global__ void epilogue1_kernel(const float* __restrict__ C1,
                                 const float* __restrict__ xs,
                                 const float* __restrict__ rs,
                                 float* __restrict__ outx,
                                 float* __restrict__ xns) {
    int idx = blockIdx.x * blockDim.x + threadIdx.x;
    if (idx >= NS * DOUT) return;
    int row = idx >> 7;
    float r = rs[row];
    float v = xs[idx] + C1[idx] / r;
    v = v > 0.f ? v : 0.f;
    outx[idx] = v;
    xns[idx] = v / r;
}

// y_new = relu(ys + C2/rt) -> d_out + NS*DOUT
__global__ void epilogue2_kernel(const float* __restrict__ C2,
                                 const float* __restrict__ ys,
                                 const float* __restrict__ rt,
                                 float* __restrict__ outy) {
    int idx = blockIdx.x * blockDim.x + threadIdx.x;
    if (idx >= NT * DOUT) return;
    int row = idx >> 7;
    float v = ys[idx] + C2[idx] / rt[row];
    v = v > 0.f ? v : 0.f;
    outy[idx] = v;
}

extern "C" void kernel_launch(void* const* d_in, const int* in_sizes, int n_in,
                              void* d_out, int out_size, void* d_ws, size_t ws_size,
                              hipStream_t stream) {
    const float* inp_s = (const float*)d_in[0];
    const float* inp_t = (const float*)d_in[1];
    const float* adj   = (const float*)d_in[2];
    const float* adj_s = (const float*)d_in[3];
    const float* adj_t = (const float*)d_in[4];
    const float* W     = (const float*)d_in[5];
    float* out = (float*)d_out;
    float* ws  = (float*)d_ws;

    float* rs  = ws + OFF_RS;
    float* rt  = ws + OFF_RT;   // deg_to, then rt in place
    float* C1  = ws + OFF_C1;
    float* C2  = ws + OFF_C2;
    float* xs  = ws + OFF_XS;
    float* ys  = ws + OFF_YS;
    float* xns = ws + OFF_XNS;

    // zero deg + C1 + C2 (contiguous region [OFF_RT, OFF_XS))
    int nz4 = (OFF_XS - OFF_RT) / 4;
    zero_kernel<<<1024, 256, 0, stream>>>(rt, nz4);

    // degrees
    rowsum_rs_kernel<<<NS, 256, 0, stream>>>(adj, adj_s, rs);
    colsum_kernel<<<dim3(NT / 256, 8), 256, 0, stream>>>(adj, NS, NT, 512, rt);
    colsum_kernel<<<dim3(NT / 256, 16), 256, 0, stream>>>(adj_t, NT, NT, 512, rt);
    finish_rt_kernel<<<NT / 256, 256, 0, stream>>>(rt);

    // projections, pre-scaled: xs = (inp_s@W)/rs, ys = (inp_t@W)/rt
    proj_scale_kernel<<<NS / 64, 256, 0, stream>>>(inp_s, W, rs, xs);
    proj_scale_kernel<<<NT / 64, 256, 0, stream>>>(inp_t, W, rt, ys);

    // C1 = adj_s@xs + adj@ys   [NS,128]
    gemm_nn_kernel<<<dim3(NS / 64, NS / CHUNK), 256, 0, stream>>>(adj_s, NS, xs, C1);
    gemm_nn_kernel<<<dim3(NS / 64, NT / CHUNK), 256, 0, stream>>>(adj, NT, ys, C1);
    epilogue1_kernel<<<(NS * DOUT) / 256, 256, 0, stream>>>(C1, xs, rs, out, xns);

    // C2 = adj_t@ys + adj^T@xns   [NT,128]
    gemm_nn_kernel<<<dim3(NT / 64, NT / CHUNK), 256, 0, stream>>>(adj_t, NT, ys, C2);
    gemm_tn_kernel<<<dim3(NT / 64, NS / CHUNK), 256, 0, stream>>>(adj, xns, C2);
    epilogue2_kernel<<<(NT * DOUT) / 256, 256, 0, stream>>>(C2, ys, rt, out + NS * DOUT);
}

// Round 3
// 652.892 us; speedup vs baseline: 1.8441x; 1.8441x over previous
//
#include <hip/hip_runtime.h>

#define NS 4096
#define NT 8192
#define DIN 256
#define DOUT 128

// float offsets into workspace
#define OFF_RS   0
#define OFF_RT   (NS)                    // 4096: holds deg_to, then rt in place
#define OFF_C1   (OFF_RT + NT)           // 12288
#define OFF_C2   (OFF_C1 + NS*DOUT)      // 536576
#define OFF_XS   (OFF_C2 + NT*DOUT)      // 1585152
#define OFF_YS   (OFF_XS + NS*DOUT)
#define OFF_XNS  (OFF_YS + NT*DOUT)

typedef __attribute__((ext_vector_type(8))) short bf8v;
typedef __attribute__((ext_vector_type(4))) float f32x4;

__device__ __forceinline__ ushort f2bf(float f) {
    // exact round-to-nearest-even fp32 -> bf16 (finite inputs only)
    unsigned x = __float_as_uint(f);
    unsigned r = (x + 0x7fffu + ((x >> 16) & 1u)) >> 16;
    return (ushort)r;
}

__global__ void zero_kernel(float* __restrict__ p, int n4) {
    int i = blockIdx.x * blockDim.x + threadIdx.x;
    int stride = gridDim.x * blockDim.x;
    float4* p4 = (float4*)p;
    float4 z = make_float4(0.f, 0.f, 0.f, 0.f);
    for (; i < n4; i += stride) p4[i] = z;
}

// rs[i] = sqrt(1 + sum_t adj[i,t] + sum_j adj_s[i,j]); one block per row
__global__ void rowsum_rs_kernel(const float* __restrict__ adj,
                                 const float* __restrict__ adj_s,
                                 float* __restrict__ rs) {
    int row = blockIdx.x;
    int tid = threadIdx.x;  // 256
    const float4* a = (const float4*)(adj + (size_t)row * NT);
    const float4* b = (const float4*)(adj_s + (size_t)row * NS);
    float sum = 0.f;
    for (int c = tid; c < NT / 4; c += 256) { float4 v = a[c]; sum += v.x + v.y + v.z + v.w; }
    for (int c = tid; c < NS / 4; c += 256) { float4 v = b[c]; sum += v.x + v.y + v.z + v.w; }
    __shared__ float red[4];
    for (int off = 32; off > 0; off >>= 1) sum += __shfl_down(sum, off, 64);
    if ((tid & 63) == 0) red[tid >> 6] = sum;
    __syncthreads();
    if (tid == 0) {
        rs[row] = sqrtf(red[0] + red[1] + red[2] + red[3] + 1.0f);
    }
}

// partial column sums, atomically accumulated into deg[t]
__global__ void colsum_kernel(const float* __restrict__ A, int nrows, int ncols,
                              int rows_per_chunk, float* __restrict__ deg) {
    int t = blockIdx.x * blockDim.x + threadIdx.x;
    int r0 = blockIdx.y * rows_per_chunk;
    int r1 = r0 + rows_per_chunk;
    if (r1 > nrows) r1 = nrows;
    float sum = 0.f;
    for (int r = r0; r < r1; ++r) sum += A[(size_t)r * ncols + t];
    unsafeAtomicAdd(&deg[t], sum);
}

__global__ void finish_rt_kernel(float* __restrict__ rt) {
    int t = blockIdx.x * blockDim.x + threadIdx.x;
    if (t < NT) rt[t] = sqrtf(rt[t] + 1.0f);
}

// out[m, :] = (inp[m, :] @ W) / rdeg[m];  inp [M, 256], W [256, 128]  (fp32 VALU)
__global__ __launch_bounds__(256)
void proj_scale_kernel(const float* __restrict__ inp,
                       const float* __restrict__ W,
                       const float* __restrict__ rdeg,
                       float* __restrict__ outp) {
    __shared__ float As[32][68];
    __shared__ float Bs[32][128];
    const int tid = threadIdx.x;
    const int m0 = blockIdx.x * 64;
    const int tx = tid & 15, ty = tid >> 4;
    const int arow = tid >> 3, acg = tid & 7;
    const int bk = tid >> 5, bng = tid & 31;

    float acc[4][8];
#pragma unroll
    for (int r = 0; r < 4; ++r)
#pragma unroll
        for (int c = 0; c < 8; ++c) acc[r][c] = 0.f;

    for (int kt = 0; kt < DIN; kt += 32) {
        const float* Ab = inp + (size_t)(m0 + arow) * DIN + kt + acg * 4;
        float4 a0 = *(const float4*)Ab;
        float4 a1 = *(const float4*)(Ab + (size_t)32 * DIN);
        const float* Bb = W + (size_t)(kt + bk) * DOUT + bng * 4;
        float4 b0 = *(const float4*)Bb;
        float4 b1 = *(const float4*)(Bb + 8 * DOUT);
        float4 b2 = *(const float4*)(Bb + 16 * DOUT);
        float4 b3 = *(const float4*)(Bb + 24 * DOUT);
        __syncthreads();
        As[acg * 4 + 0][arow] = a0.x;
        As[acg * 4 + 1][arow] = a0.y;
        As[acg * 4 + 2][arow] = a0.z;
        As[acg * 4 + 3][arow] = a0.w;
        As[acg * 4 + 0][arow + 32] = a1.x;
        As[acg * 4 + 1][arow + 32] = a1.y;
        As[acg * 4 + 2][arow + 32] = a1.z;
        As[acg * 4 + 3][arow + 32] = a1.w;
        *(float4*)&Bs[bk][bng * 4] = b0;
        *(float4*)&Bs[bk + 8][bng * 4] = b1;
        *(float4*)&Bs[bk + 16][bng * 4] = b2;
        *(float4*)&Bs[bk + 24][bng * 4] = b3;
        __syncthreads();
#pragma unroll
        for (int k = 0; k < 32; ++k) {
            float4 av = *(const float4*)&As[k][ty * 4];
            float4 bv0 = *(const float4*)&Bs[k][tx * 4];
            float4 bv1 = *(const float4*)&Bs[k][tx * 4 + 64];
            float a[4] = {av.x, av.y, av.z, av.w};
            float b[8] = {bv0.x, bv0.y, bv0.z, bv0.w, bv1.x, bv1.y, bv1.z, bv1.w};
#pragma unroll
            for (int r = 0; r < 4; ++r)
#pragma unroll
                for (int c = 0; c < 8; ++c) acc[r][c] = fmaf(a[r], b[c], acc[r][c]);
        }
    }
#pragma unroll
    for (int r = 0; r < 4; ++r) {
        int row = m0 + ty * 4 + r;
        float rd = rdeg[row];
        float* orow = outp + (size_t)row * DOUT;
#pragma unroll
        for (int c = 0; c < 4; ++c) {
            orow[tx * 4 + c] = acc[r][c] / rd;
            orow[tx * 4 + 64 + c] = acc[r][4 + c] / rd;
        }
    }
}

// C[m0:m0+128, 0:128] += op(A)[m0:m0+128, k0:k0+kchunk] @ B[k0:k0+kchunk, 0:128]
// TRANS=0: op(A)=A, A[m][k] row-major with pitch lda.
// TRANS=1: op(A)=A^T, A[k][m] row-major with pitch lda (adj: k in [0,NS), m in [0,NT)).
// fp32 global -> bf16 LDS -> mfma_f32_16x16x32_bf16, fp32 atomic accumulate into C.
template<int TRANS>
__global__ __launch_bounds__(256)
void gemm_mfma_kernel(const float* __restrict__ A, int lda,
                      const float* __restrict__ B,
                      float* __restrict__ C, int kchunk) {
    __shared__ ushort As[128][40];   // [m][k], pitch 80 B (2-way conflict = free)
    __shared__ ushort Bs[128][40];   // [n][k] (B transposed)
    const int tid = threadIdx.x;
    const int m0 = blockIdx.x * 128;
    const int k0 = blockIdx.y * kchunk;
    const int lane = tid & 63, wid = tid >> 6;
    const int wm = (wid >> 1) * 64, wn = (wid & 1) * 64;
    const int r16 = lane & 15, kg = lane >> 4;

    // staging thread mapping
    const int s_kr = tid >> 3, s_f4 = tid & 7;   // B and TRANS-A: k-row, f4 col group
    const int a_r = tid >> 1, a_seg = tid & 1;   // NN-A: m-row, 16-float segment

    f32x4 acc[4][4];
#pragma unroll
    for (int i = 0; i < 4; ++i)
#pragma unroll
        for (int j = 0; j < 4; ++j) acc[i][j] = (f32x4)(0.f);

    float4 aP[4], bP[4];
    // prefetch kt = 0
    {
        const float* Bb = B + (size_t)(k0 + s_kr) * DOUT + s_f4 * 4;
#pragma unroll
        for (int i = 0; i < 4; ++i) bP[i] = *(const float4*)(Bb + i * 32);
        if (TRANS) {
            const float* Ab = A + (size_t)(k0 + s_kr) * lda + m0 + s_f4 * 4;
#pragma unroll
            for (int i = 0; i < 4; ++i) aP[i] = *(const float4*)(Ab + i * 32);
        } else {
            const float* Ab = A + (size_t)(m0 + a_r) * lda + k0 + a_seg * 16;
#pragma unroll
            for (int i = 0; i < 4; ++i) aP[i] = *(const float4*)(Ab + i * 4);
        }
    }

    for (int kt = 0; kt < kchunk; kt += 32) {
        __syncthreads();   // previous iteration's LDS reads complete
        // convert + store staged tile
        if (TRANS) {
#pragma unroll
            for (int i = 0; i < 4; ++i) {
                int m = s_f4 * 4 + i * 32;
                As[m + 0][s_kr] = f2bf(aP[i].x);
                As[m + 1][s_kr] = f2bf(aP[i].y);
                As[m + 2][s_kr] = f2bf(aP[i].z);
                As[m + 3][s_kr] = f2bf(aP[i].w);
            }
        } else {
            bf8v w0, w1;
            w0[0] = (short)f2bf(aP[0].x); w0[1] = (short)f2bf(aP[0].y);
            w0[2] = (short)f2bf(aP[0].z); w0[3] = (short)f2bf(aP[0].w);
            w0[4] = (short)f2bf(aP[1].x); w0[5] = (short)f2bf(aP[1].y);
            w0[6] = (short)f2bf(aP[1].z); w0[7] = (short)f2bf(aP[1].w);
            w1[0] = (short)f2bf(aP[2].x); w1[1] = (short)f2bf(aP[2].y);
            w1[2] = (short)f2bf(aP[2].z); w1[3] = (short)f2bf(aP[2].w);
            w1[4] = (short)f2bf(aP[3].x); w1[5] = (short)f2bf(aP[3].y);
            w1[6] = (short)f2bf(aP[3].z); w1[7] = (short)f2bf(aP[3].w);
            *(bf8v*)&As[a_r][a_seg * 16] = w0;
            *(bf8v*)&As[a_r][a_seg * 16 + 8] = w1;
        }
#pragma unroll
        for (int i = 0; i < 4; ++i) {
            int n = s_f4 * 4 + i * 32;
            Bs[n + 0][s_kr] = f2bf(bP[i].x);
            Bs[n + 1][s_kr] = f2bf(bP[i].y);
            Bs[n + 2][s_kr] = f2bf(bP[i].z);
            Bs[n + 3][s_kr] = f2bf(bP[i].w);
        }
        __syncthreads();

        // issue next tile's global loads (overlap with MFMA below)
        if (kt + 32 < kchunk) {
            const float* Bb = B + (size_t)(k0 + kt + 32 + s_kr) * DOUT + s_f4 * 4;
#pragma unroll
            for (int i = 0; i < 4; ++i) bP[i] = *(const float4*)(Bb + i * 32);
            if (TRANS) {
                const float* Ab = A + (size_t)(k0 + kt + 32 + s_kr) * lda + m0 + s_f4 * 4;
#pragma unroll
                for (int i = 0; i < 4; ++i) aP[i] = *(const float4*)(Ab + i * 32);
            } else {
                const float* Ab = A + (size_t)(m0 + a_r) * lda + k0 + kt + 32 + a_seg * 16;
#pragma unroll
                for (int i = 0; i < 4; ++i) aP[i] = *(const float4*)(Ab + i * 4);
            }
        }

        // fragments + MFMA
        bf8v af[4], bf[4];
#pragma unroll
        for (int f = 0; f < 4; ++f) af[f] = *(const bf8v*)&As[wm + f * 16 + r16][kg * 8];
#pragma unroll
        for (int f = 0; f < 4; ++f) bf[f] = *(const bf8v*)&Bs[wn + f * 16 + r16][kg * 8];
#pragma unroll
        for (int i = 0; i < 4; ++i)
#pragma unroll
            for (int j = 0; j < 4; ++j)
                acc[i][j] = __builtin_amdgcn_mfma_f32_16x16x32_bf16(af[i], bf[j], acc[i][j], 0, 0, 0);
    }

    // epilogue: atomic accumulate (split-K)
    const int crow0 = m0 + wm + (lane >> 4) * 4;
#pragma unroll
    for (int i = 0; i < 4; ++i) {
#pragma unroll
        for (int j = 0; j < 4; ++j) {
            float* base = C + (size_t)(crow0 + i * 16) * DOUT + wn + j * 16 + r16;
            unsafeAtomicAdd(base + 0 * DOUT, acc[i][j][0]);
            unsafeAtomicAdd(base + 1 * DOUT, acc[i][j][1]);
            unsafeAtomicAdd(base + 2 * DOUT, acc[i][j][2]);
            unsafeAtomicAdd(base + 3 * DOUT, acc[i][j][3]);
        }
    }
}

// x_new = relu(xs + C1/rs) -> d_out;  xns = x_new/rs -> ws
__global__ void epilogue1_kernel(const float* __restrict__ C1,
                                 const float* __restrict__ xs,
                                 const float* __restrict__ rs,
                                 float* __restrict__ outx,
                                 float* __restrict__ xns) {
    int idx = blockIdx.x * blockDim.x + threadIdx.x;
    if (idx >= NS * DOUT) return;
    int row = idx >> 7;
    float r = rs[row];
    float v = xs[idx] + C1[idx] / r;
    v = v > 0.f ? v : 0.f;
    outx[idx] = v;
    xns[idx] = v / r;
}

// y_new = relu(ys + C2/rt) -> d_out + NS*DOUT
__global__ void epilogue2_kernel(const float* __restrict__ C2,
                                 const float* __restrict__ ys,
                                 const float* __restrict__ rt,
                                 float* __restrict__ outy) {
    int idx = blockIdx.x * blockDim.x + threadIdx.x;
    if (idx >= NT * DOUT) return;
    int row = idx >> 7;
    float v = ys[idx] + C2[idx] / rt[row];
    v = v > 0.f ? v : 0.f;
    outy[idx] = v;
}

extern "C" void kernel_launch(void* const* d_in, const int* in_sizes, int n_in,
                              void* d_out, int out_size, void* d_ws, size_t ws_size,
                              hipStream_t stream) {
    const float* inp_s = (const float*)d_in[0];
    const float* inp_t = (const float*)d_in[1];
    const float* adj   = (const float*)d_in[2];
    const float* adj_s = (const float*)d_in[3];
    const float* adj_t = (const float*)d_in[4];
    const float* W     = (const float*)d_in[5];
    float* out = (float*)d_out;
    float* ws  = (float*)d_ws;

    float* rs  = ws + OFF_RS;
    float* rt  = ws + OFF_RT;   // deg_to, then rt in place
    float* C1  = ws + OFF_C1;
    float* C2  = ws + OFF_C2;
    float* xs  = ws + OFF_XS;
    float* ys  = ws + OFF_YS;
    float* xns = ws + OFF_XNS;

    // zero deg + C1 + C2 (contiguous region [OFF_RT, OFF_XS))
    int nz4 = (OFF_XS - OFF_RT) / 4;
    zero_kernel<<<1024, 256, 0, stream>>>(rt, nz4);

    // degrees (fp32, exact)
    rowsum_rs_kernel<<<NS, 256, 0, stream>>>(adj, adj_s, rs);
    colsum_kernel<<<dim3(NT / 256, 8), 256, 0, stream>>>(adj, NS, NT, 512, rt);
    colsum_kernel<<<dim3(NT / 256, 16), 256, 0, stream>>>(adj_t, NT, NT, 512, rt);
    finish_rt_kernel<<<NT / 256, 256, 0, stream>>>(rt);

    // projections, pre-scaled: xs = (inp_s@W)/rs, ys = (inp_t@W)/rt
    proj_scale_kernel<<<NS / 64, 256, 0, stream>>>(inp_s, W, rs, xs);
    proj_scale_kernel<<<NT / 64, 256, 0, stream>>>(inp_t, W, rt, ys);

    // C1 = adj_s@xs + adj@ys   [NS,128]   (bf16 MFMA, split-K atomics)
    gemm_mfma_kernel<0><<<dim3(NS / 128, 8), 256, 0, stream>>>(adj_s, NS, xs, C1, NS / 8);
    gemm_mfma_kernel<0><<<dim3(NS / 128, 8), 256, 0, stream>>>(adj, NT, ys, C1, NT / 8);
    epilogue1_kernel<<<(NS * DOUT) / 256, 256, 0, stream>>>(C1, xs, rs, out, xns);

    // C2 = adj_t@ys + adj^T@xns   [NT,128]
    gemm_mfma_kernel<0><<<dim3(NT / 128, 8), 256, 0, stream>>>(adj_t, NT, ys, C2, NT / 8);
    gemm_mfma_kernel<1><<<dim3(NT / 128, 8), 256, 0, stream>>>(adj, NT, xns, C2, NS / 8);
    epilogue2_kernel<<<(NT * DOUT) / 256, 256, 0, stream>>>(C2, ys, rt, out + NS * DOUT);
}

// Round 4
// 427.822 us; speedup vs baseline: 2.8143x; 1.5261x over previous
//
#include <hip/hip_runtime.h>

#define NS 4096
#define NT 8192
#define DIN 256
#define DOUT 128

// float offsets into workspace
#define OFF_RS   0
#define OFF_RT   (NS)                    // 4096: holds deg_to, then rt in place
#define OFF_C1   (OFF_RT + NT)           // 12288
#define OFF_C2   (OFF_C1 + NS*DOUT)      // 536576
#define OFF_XS   (OFF_C2 + NT*DOUT)      // 1585152
#define OFF_YS   (OFF_XS + NS*DOUT)
#define OFF_XNS  (OFF_YS + NT*DOUT)

typedef __attribute__((ext_vector_type(8))) short bf8v;
typedef __attribute__((ext_vector_type(4))) float f32x4;

__device__ __forceinline__ ushort f2bf(float f) {
    // exact round-to-nearest-even fp32 -> bf16 (finite inputs only)
    unsigned x = __float_as_uint(f);
    unsigned r = (x + 0x7fffu + ((x >> 16) & 1u)) >> 16;
    return (ushort)r;
}

__global__ void zero_kernel(float* __restrict__ p, int n4) {
    int i = blockIdx.x * blockDim.x + threadIdx.x;
    int stride = gridDim.x * blockDim.x;
    float4* p4 = (float4*)p;
    float4 z = make_float4(0.f, 0.f, 0.f, 0.f);
    for (; i < n4; i += stride) p4[i] = z;
}

// rs[row] = sqrt(1 + sum adj[row,:] + sum adj_s[row,:]); one wave per row
__global__ __launch_bounds__(256)
void rowsum_rs_kernel(const float* __restrict__ adj,
                      const float* __restrict__ adj_s,
                      float* __restrict__ rs) {
    const int wid = threadIdx.x >> 6;
    const int lane = threadIdx.x & 63;
    const int row = blockIdx.x * 4 + wid;
    const float4* a = (const float4*)(adj + (size_t)row * NT);
    const float4* b = (const float4*)(adj_s + (size_t)row * NS);
    float sum = 0.f;
#pragma unroll 4
    for (int c = lane; c < NT / 4; c += 64) { float4 v = a[c]; sum += v.x + v.y + v.z + v.w; }
#pragma unroll 4
    for (int c = lane; c < NS / 4; c += 64) { float4 v = b[c]; sum += v.x + v.y + v.z + v.w; }
    for (int off = 32; off > 0; off >>= 1) sum += __shfl_down(sum, off, 64);
    if (lane == 0) rs[row] = sqrtf(sum + 1.0f);
}

// partial column sums, float4 per thread, atomically accumulated into deg[.]
__global__ __launch_bounds__(256)
void colsum_v4_kernel(const float* __restrict__ A, int nrows, int ncols,
                      int rows_per_chunk, float* __restrict__ deg) {
    const int c4 = blockIdx.x * blockDim.x + threadIdx.x;   // float4 column index
    const int r0 = blockIdx.y * rows_per_chunk;
    int r1 = r0 + rows_per_chunk;
    if (r1 > nrows) r1 = nrows;
    const float4* A4 = (const float4*)A;
    const int pitch4 = ncols >> 2;
    float sx = 0.f, sy = 0.f, sz = 0.f, sw = 0.f;
    for (int r = r0; r < r1; ++r) {
        float4 v = A4[(size_t)r * pitch4 + c4];
        sx += v.x; sy += v.y; sz += v.z; sw += v.w;
    }
    float* d = deg + c4 * 4;
    unsafeAtomicAdd(d + 0, sx);
    unsafeAtomicAdd(d + 1, sy);
    unsafeAtomicAdd(d + 2, sz);
    unsafeAtomicAdd(d + 3, sw);
}

__global__ void finish_rt_kernel(float* __restrict__ rt) {
    int t = blockIdx.x * blockDim.x + threadIdx.x;
    if (t < NT) rt[t] = sqrtf(rt[t] + 1.0f);
}

// out[m, :] = (inp[m, :] @ W) / rdeg[m];  inp [M, 256], W [256, 128]  (fp32 VALU)
__global__ __launch_bounds__(256)
void proj_scale_kernel(const float* __restrict__ inp,
                       const float* __restrict__ W,
                       const float* __restrict__ rdeg,
                       float* __restrict__ outp) {
    __shared__ float As[32][68];
    __shared__ float Bs[32][128];
    const int tid = threadIdx.x;
    const int m0 = blockIdx.x * 64;
    const int tx = tid & 15, ty = tid >> 4;
    const int arow = tid >> 3, acg = tid & 7;
    const int bk = tid >> 5, bng = tid & 31;

    float acc[4][8];
#pragma unroll
    for (int r = 0; r < 4; ++r)
#pragma unroll
        for (int c = 0; c < 8; ++c) acc[r][c] = 0.f;

    for (int kt = 0; kt < DIN; kt += 32) {
        const float* Ab = inp + (size_t)(m0 + arow) * DIN + kt + acg * 4;
        float4 a0 = *(const float4*)Ab;
        float4 a1 = *(const float4*)(Ab + (size_t)32 * DIN);
        const float* Bb = W + (size_t)(kt + bk) * DOUT + bng * 4;
        float4 b0 = *(const float4*)Bb;
        float4 b1 = *(const float4*)(Bb + 8 * DOUT);
        float4 b2 = *(const float4*)(Bb + 16 * DOUT);
        float4 b3 = *(const float4*)(Bb + 24 * DOUT);
        __syncthreads();
        As[acg * 4 + 0][arow] = a0.x;
        As[acg * 4 + 1][arow] = a0.y;
        As[acg * 4 + 2][arow] = a0.z;
        As[acg * 4 + 3][arow] = a0.w;
        As[acg * 4 + 0][arow + 32] = a1.x;
        As[acg * 4 + 1][arow + 32] = a1.y;
        As[acg * 4 + 2][arow + 32] = a1.z;
        As[acg * 4 + 3][arow + 32] = a1.w;
        *(float4*)&Bs[bk][bng * 4] = b0;
        *(float4*)&Bs[bk + 8][bng * 4] = b1;
        *(float4*)&Bs[bk + 16][bng * 4] = b2;
        *(float4*)&Bs[bk + 24][bng * 4] = b3;
        __syncthreads();
#pragma unroll
        for (int k = 0; k < 32; ++k) {
            float4 av = *(const float4*)&As[k][ty * 4];
            float4 bv0 = *(const float4*)&Bs[k][tx * 4];
            float4 bv1 = *(const float4*)&Bs[k][tx * 4 + 64];
            float a[4] = {av.x, av.y, av.z, av.w};
            float b[8] = {bv0.x, bv0.y, bv0.z, bv0.w, bv1.x, bv1.y, bv1.z, bv1.w};
#pragma unroll
            for (int r = 0; r < 4; ++r)
#pragma unroll
                for (int c = 0; c < 8; ++c) acc[r][c] = fmaf(a[r], b[c], acc[r][c]);
        }
    }
#pragma unroll
    for (int r = 0; r < 4; ++r) {
        int row = m0 + ty * 4 + r;
        float rd = rdeg[row];
        float* orow = outp + (size_t)row * DOUT;
#pragma unroll
        for (int c = 0; c < 4; ++c) {
            orow[tx * 4 + c] = acc[r][c] / rd;
            orow[tx * 4 + 64 + c] = acc[r][4 + c] / rd;
        }
    }
}

// C[m0:m0+128, 0:128] += op(A)[m0:m0+128, k0:k0+kchunk] @ B[k0:k0+kchunk, 0:128]
// TRANS=0: op(A)=A row-major pitch lda.  TRANS=1: op(A)=A^T, A[k][m] pitch lda.
// fp32 global -> bf16 LDS -> mfma_f32_16x16x32_bf16, fp32 atomic accumulate into C.
template<int TRANS>
__global__ __launch_bounds__(256)
void gemm_mfma_kernel(const float* __restrict__ A, int lda,
                      const float* __restrict__ B,
                      float* __restrict__ C, int kchunk) {
    __shared__ ushort As[128][40];   // [m][k], pitch 80 B (2-way conflict = free)
    __shared__ ushort Bs[128][40];   // [n][k] (B transposed)
    const int tid = threadIdx.x;
    const int m0 = blockIdx.x * 128;
    const int k0 = blockIdx.y * kchunk;
    const int lane = tid & 63, wid = tid >> 6;
    const int wm = (wid >> 1) * 64, wn = (wid & 1) * 64;
    const int r16 = lane & 15, kg = lane >> 4;

    // staging thread mapping
    const int s_kr = tid >> 3, s_f4 = tid & 7;   // B and TRANS-A: k-row, f4 col group
    const int a_r = tid >> 1, a_seg = tid & 1;   // NN-A: m-row, 16-float segment

    f32x4 acc[4][4];
#pragma unroll
    for (int i = 0; i < 4; ++i)
#pragma unroll
        for (int j = 0; j < 4; ++j) acc[i][j] = (f32x4)(0.f);

    float4 aP[4], bP[4];
    // prefetch kt = 0
    {
        const float* Bb = B + (size_t)(k0 + s_kr) * DOUT + s_f4 * 4;
#pragma unroll
        for (int i = 0; i < 4; ++i) bP[i] = *(const float4*)(Bb + i * 32);
        if (TRANS) {
            const float* Ab = A + (size_t)(k0 + s_kr) * lda + m0 + s_f4 * 4;
#pragma unroll
            for (int i = 0; i < 4; ++i) aP[i] = *(const float4*)(Ab + i * 32);
        } else {
            const float* Ab = A + (size_t)(m0 + a_r) * lda + k0 + a_seg * 16;
#pragma unroll
            for (int i = 0; i < 4; ++i) aP[i] = *(const float4*)(Ab + i * 4);
        }
    }

    for (int kt = 0; kt < kchunk; kt += 32) {
        __syncthreads();   // previous iteration's LDS reads complete
        // convert + store staged tile
        if (TRANS) {
#pragma unroll
            for (int i = 0; i < 4; ++i) {
                int m = s_f4 * 4 + i * 32;
                As[m + 0][s_kr] = f2bf(aP[i].x);
                As[m + 1][s_kr] = f2bf(aP[i].y);
                As[m + 2][s_kr] = f2bf(aP[i].z);
                As[m + 3][s_kr] = f2bf(aP[i].w);
            }
        } else {
            bf8v w0, w1;
            w0[0] = (short)f2bf(aP[0].x); w0[1] = (short)f2bf(aP[0].y);
            w0[2] = (short)f2bf(aP[0].z); w0[3] = (short)f2bf(aP[0].w);
            w0[4] = (short)f2bf(aP[1].x); w0[5] = (short)f2bf(aP[1].y);
            w0[6] = (short)f2bf(aP[1].z); w0[7] = (short)f2bf(aP[1].w);
            w1[0] = (short)f2bf(aP[2].x); w1[1] = (short)f2bf(aP[2].y);
            w1[2] = (short)f2bf(aP[2].z); w1[3] = (short)f2bf(aP[2].w);
            w1[4] = (short)f2bf(aP[3].x); w1[5] = (short)f2bf(aP[3].y);
            w1[6] = (short)f2bf(aP[3].z); w1[7] = (short)f2bf(aP[3].w);
            *(bf8v*)&As[a_r][a_seg * 16] = w0;
            *(bf8v*)&As[a_r][a_seg * 16 + 8] = w1;
        }
#pragma unroll
        for (int i = 0; i < 4; ++i) {
            int n = s_f4 * 4 + i * 32;
            Bs[n + 0][s_kr] = f2bf(bP[i].x);
            Bs[n + 1][s_kr] = f2bf(bP[i].y);
            Bs[n + 2][s_kr] = f2bf(bP[i].z);
            Bs[n + 3][s_kr] = f2bf(bP[i].w);
        }
        __syncthreads();

        // issue next tile's global loads (overlap with MFMA below)
        if (kt + 32 < kchunk) {
            const float* Bb = B + (size_t)(k0 + kt + 32 + s_kr) * DOUT + s_f4 * 4;
#pragma unroll
            for (int i = 0; i < 4; ++i) bP[i] = *(const float4*)(Bb + i * 32);
            if (TRANS) {
                const float* Ab = A + (size_t)(k0 + kt + 32 + s_kr) * lda + m0 + s_f4 * 4;
#pragma unroll
                for (int i = 0; i < 4; ++i) aP[i] = *(const float4*)(Ab + i * 32);
            } else {
                const float* Ab = A + (size_t)(m0 + a_r) * lda + k0 + kt + 32 + a_seg * 16;
#pragma unroll
                for (int i = 0; i < 4; ++i) aP[i] = *(const float4*)(Ab + i * 4);
            }
        }

        // fragments + MFMA
        bf8v af[4], bf[4];
#pragma unroll
        for (int f = 0; f < 4; ++f) af[f] = *(const bf8v*)&As[wm + f * 16 + r16][kg * 8];
#pragma unroll
        for (int f = 0; f < 4; ++f) bf[f] = *(const bf8v*)&Bs[wn + f * 16 + r16][kg * 8];
#pragma unroll
        for (int i = 0; i < 4; ++i)
#pragma unroll
            for (int j = 0; j < 4; ++j)
                acc[i][j] = __builtin_amdgcn_mfma_f32_16x16x32_bf16(af[i], bf[j], acc[i][j], 0, 0, 0);
    }

    // epilogue: atomic accumulate (split-K)
    const int crow0 = m0 + wm + (lane >> 4) * 4;
#pragma unroll
    for (int i = 0; i < 4; ++i) {
#pragma unroll
        for (int j = 0; j < 4; ++j) {
            float* base = C + (size_t)(crow0 + i * 16) * DOUT + wn + j * 16 + r16;
            unsafeAtomicAdd(base + 0 * DOUT, acc[i][j][0]);
            unsafeAtomicAdd(base + 1 * DOUT, acc[i][j][1]);
            unsafeAtomicAdd(base + 2 * DOUT, acc[i][j][2]);
            unsafeAtomicAdd(base + 3 * DOUT, acc[i][j][3]);
        }
    }
}

// x_new = relu(xs + C1/rs) -> d_out;  xns = x_new/rs -> ws
__global__ void epilogue1_kernel(const float* __restrict__ C1,
                                 const float* __restrict__ xs,
                                 const float* __restrict__ rs,
                                 float* __restrict__ outx,
                                 float* __restrict__ xns) {
    int idx = blockIdx.x * blockDim.x + threadIdx.x;
    if (idx >= NS * DOUT) return;
    int row = idx >> 7;
    float r = rs[row];
    float v = xs[idx] + C1[idx] / r;
    v = v > 0.f ? v : 0.f;
    outx[idx] = v;
    xns[idx] = v / r;
}

// y_new = relu(ys + C2/rt) -> d_out + NS*DOUT
__global__ void epilogue2_kernel(const float* __restrict__ C2,
                                 const float* __restrict__ ys,
                                 const float* __restrict__ rt,
                                 float* __restrict__ outy) {
    int idx = blockIdx.x * blockDim.x + threadIdx.x;
    if (idx >= NT * DOUT) return;
    int row = idx >> 7;
    float v = ys[idx] + C2[idx] / rt[row];
    v = v > 0.f ? v : 0.f;
    outy[idx] = v;
}

extern "C" void kernel_launch(void* const* d_in, const int* in_sizes, int n_in,
                              void* d_out, int out_size, void* d_ws, size_t ws_size,
                              hipStream_t stream) {
    const float* inp_s = (const float*)d_in[0];
    const float* inp_t = (const float*)d_in[1];
    const float* adj   = (const float*)d_in[2];
    const float* adj_s = (const float*)d_in[3];
    const float* adj_t = (const float*)d_in[4];
    const float* W     = (const float*)d_in[5];
    float* out = (float*)d_out;
    float* ws  = (float*)d_ws;

    float* rs  = ws + OFF_RS;
    float* rt  = ws + OFF_RT;   // deg_to, then rt in place
    float* C1  = ws + OFF_C1;
    float* C2  = ws + OFF_C2;
    float* xs  = ws + OFF_XS;
    float* ys  = ws + OFF_YS;
    float* xns = ws + OFF_XNS;

    // zero deg + C1 + C2 (contiguous region [OFF_RT, OFF_XS))
    int nz4 = (OFF_XS - OFF_RT) / 4;
    zero_kernel<<<1024, 256, 0, stream>>>(rt, nz4);

    // degrees (fp32, exact)
    rowsum_rs_kernel<<<NS / 4, 256, 0, stream>>>(adj, adj_s, rs);
    colsum_v4_kernel<<<dim3(NT / 1024, 128), 256, 0, stream>>>(adj, NS, NT, 32, rt);
    colsum_v4_kernel<<<dim3(NT / 1024, 128), 256, 0, stream>>>(adj_t, NT, NT, 64, rt);
    finish_rt_kernel<<<NT / 256, 256, 0, stream>>>(rt);

    // projections, pre-scaled: xs = (inp_s@W)/rs, ys = (inp_t@W)/rt
    proj_scale_kernel<<<NS / 64, 256, 0, stream>>>(inp_s, W, rs, xs);
    proj_scale_kernel<<<NT / 64, 256, 0, stream>>>(inp_t, W, rt, ys);

    // C1 = adj_s@xs + adj@ys   [NS,128]   (bf16 MFMA, split-K atomics)
    gemm_mfma_kernel<0><<<dim3(NS / 128, 8), 256, 0, stream>>>(adj_s, NS, xs, C1, NS / 8);
    gemm_mfma_kernel<0><<<dim3(NS / 128, 8), 256, 0, stream>>>(adj, NT, ys, C1, NT / 8);
    epilogue1_kernel<<<(NS * DOUT) / 256, 256, 0, stream>>>(C1, xs, rs, out, xns);

    // C2 = adj_t@ys + adj^T@xns   [NT,128]
    gemm_mfma_kernel<0><<<dim3(NT / 128, 8), 256, 0, stream>>>(adj_t, NT, ys, C2, NT / 8);
    gemm_mfma_kernel<1><<<dim3(NT / 128, 8), 256, 0, stream>>>(adj, NT, xns, C2, NS / 8);
    epilogue2_kernel<<<(NT * DOUT) / 256, 256, 0, stream>>>(C2, ys, rt, out + NS * DOUT);
}